// Round 1
// baseline (1249.158 us; speedup 1.0000x reference)
//
#include <hip/hip_runtime.h>
#include <hip/hip_bf16.h>
#include <stdint.h>

typedef __attribute__((ext_vector_type(8))) short short8;
typedef __attribute__((ext_vector_type(4))) float f32x4;

__device__ __forceinline__ float b2f(short s) {
    union { unsigned u; float f; } v; v.u = ((unsigned)(unsigned short)s) << 16; return v.f;
}
__device__ __forceinline__ short f2b(float f) {
    union { float f; unsigned u; } v; v.f = f;
    unsigned r = (v.u + 0x7FFF + ((v.u >> 16) & 1)) >> 16;
    return (short)r;
}

// async global->LDS, 16B per lane. LDS dest is wave-uniform base + lane*16.
__device__ __forceinline__ void gload16(const void* g, void* l) {
    __builtin_amdgcn_global_load_lds(
        (const __attribute__((address_space(1))) void*)(uintptr_t)g,
        (__attribute__((address_space(3))) void*)(uintptr_t)l,
        16, 0, 0);
}

// ---------------- cast fp32 -> bf16 (8 elems/thread) ----------------
__global__ __launch_bounds__(256) void cast_bf16_kernel(
    const float* __restrict__ src, short* __restrict__ dst, int n8) {
    int i = blockIdx.x * 256 + threadIdx.x;
    if (i >= n8) return;
    const float4* s = (const float4*)src + (size_t)i * 2;
    float4 x0 = s[0], x1 = s[1];
    short8 o;
    o[0] = f2b(x0.x); o[1] = f2b(x0.y); o[2] = f2b(x0.z); o[3] = f2b(x0.w);
    o[4] = f2b(x1.x); o[5] = f2b(x1.y); o[6] = f2b(x1.z); o[7] = f2b(x1.w);
    *((short8*)dst + i) = o;
}

// ---------- transpose-cast W[K,N] f32 -> Wt[N,K] bf16 (8 k per thread) ----------
__global__ __launch_bounds__(256) void transpose_cast_kernel(
    const float* __restrict__ W, short* __restrict__ Wt, int K, int N, int total) {
    int t = blockIdx.x * 256 + threadIdx.x;
    if (t >= total) return;
    const float* src = W + (size_t)blockIdx.y * K * N;
    short* dst = Wt + (size_t)blockIdx.y * K * N;
    int n = t % N;
    int k0 = (t / N) * 8;
    short8 o;
#pragma unroll
    for (int i = 0; i < 8; i++) o[i] = f2b(src[(size_t)(k0 + i) * N + n]);
    *(short8*)(dst + (size_t)n * K + k0) = o;
}

// ---------------- generic C = relu(A @ Bt^T + bias), bf16 out ----------------
// A[M,K] bf16 row-major, Bt[N,K] bf16 row-major. Tile 128x128, 4 waves (2x2 of 64x64).
__global__ __launch_bounds__(256, 3)
void gemm_bt_bias_relu(const short* __restrict__ A, const short* __restrict__ Bt,
                       const float* __restrict__ bias, short* __restrict__ C,
                       int M, int N, int K) {
    __shared__ __align__(16) short As[128 * 32];
    __shared__ __align__(16) short Bs[128 * 32];
    const int tid = threadIdx.x;
    const int w = tid >> 6, lane = tid & 63;
    const int tm = blockIdx.y * 128, tn = blockIdx.x * 128;
    const int wm = (w & 1) * 64, wn = (w >> 1) * 64;
    const int r = lane & 15, q = lane >> 4, qk = q * 8;

    // staging: tile [128][32] = 8 chunks of 1KB; this wave stages chunks 2w, 2w+1
    const int c0 = w * 2, c1 = w * 2 + 1;
    const int srow0 = c0 * 16 + (lane >> 2);
    const int srow1 = c1 * 16 + (lane >> 2);
    const int skk = (lane & 3) * 8;
    const short* gA0 = A + (size_t)(tm + srow0) * K + skk;
    const short* gA1 = A + (size_t)(tm + srow1) * K + skk;
    const short* gB0 = Bt + (size_t)(tn + srow0) * K + skk;
    const short* gB1 = Bt + (size_t)(tn + srow1) * K + skk;
    short* lA0 = &As[c0 * 512]; short* lA1 = &As[c1 * 512];
    short* lB0 = &Bs[c0 * 512]; short* lB1 = &Bs[c1 * 512];

    f32x4 acc[4][4] = {};
    for (int k0 = 0; k0 < K; k0 += 32) {
        gload16(gA0 + k0, lA0);
        gload16(gA1 + k0, lA1);
        gload16(gB0 + k0, lB0);
        gload16(gB1 + k0, lB1);
        __syncthreads();
        short8 a[4], b[4];
#pragma unroll
        for (int i = 0; i < 4; i++) a[i] = *(const short8*)&As[(wm + i * 16 + r) * 32 + qk];
#pragma unroll
        for (int j = 0; j < 4; j++) b[j] = *(const short8*)&Bs[(wn + j * 16 + r) * 32 + qk];
#pragma unroll
        for (int i = 0; i < 4; i++)
#pragma unroll
            for (int j = 0; j < 4; j++)
                acc[i][j] = __builtin_amdgcn_mfma_f32_16x16x32_bf16(a[i], b[j], acc[i][j], 0, 0, 0);
        __syncthreads();
    }
#pragma unroll
    for (int j = 0; j < 4; j++) {
        int col = tn + wn + j * 16 + r;
        float bj = bias[col];
#pragma unroll
        for (int i = 0; i < 4; i++)
#pragma unroll
            for (int rr = 0; rr < 4; rr++) {
                int row = tm + wm + i * 16 + q * 4 + rr;
                float v = fmaxf(acc[i][j][rr] + bj, 0.f);
                C[(size_t)row * N + col] = f2b(v);
            }
    }
}

// ---------------- selector last layer + softmax ----------------
// s1[B,128] bf16, Ws2t[16,128] bf16 -> wsel[B,16] f32. 16 lanes per row.
__global__ __launch_bounds__(256)
void selector_softmax(const short* __restrict__ s1, const short* __restrict__ Ws2t,
                      const float* __restrict__ bs2, float* __restrict__ wsel) {
    int tid = threadIdx.x;
    int row = blockIdx.x * 16 + (tid >> 4);
    int e = tid & 15;
    const short8* a = (const short8*)(s1 + (size_t)row * 128);
    const short8* b = (const short8*)(Ws2t + (size_t)e * 128);
    float acc = bs2[e];
#pragma unroll
    for (int kk = 0; kk < 16; ++kk) {
        short8 av = a[kk], bv = b[kk];
#pragma unroll
        for (int i = 0; i < 8; i++) acc = fmaf(b2f(av[i]), b2f(bv[i]), acc);
    }
    float m = acc;
#pragma unroll
    for (int off = 8; off >= 1; off >>= 1) m = fmaxf(m, __shfl_xor(m, off, 16));
    float ex = __expf(acc - m);
    float s = ex;
#pragma unroll
    for (int off = 8; off >= 1; off >>= 1) s += __shfl_xor(s, off, 16);
    wsel[(size_t)row * 16 + e] = ex / s;
}

// ---------------- fused experts + weighted fusion ----------------
// h[B,512] bf16; We1t[16][256][512] bf16; We2t[16][32][256] bf16;
// be1[16,256], be2[16,32], wsel[B,16] f32 -> out[B,32] f32.
// Block = 128 rows, loops 16 experts; eh kept in padded LDS; fused acc in regs.
__global__ __launch_bounds__(256, 2)
void expert_fused(const short* __restrict__ h, const short* __restrict__ We1t,
                  const short* __restrict__ We2t, const float* __restrict__ be1,
                  const float* __restrict__ be2, const float* __restrict__ wsel,
                  float* __restrict__ out) {
    __shared__ __align__(16) short As[128 * 32];
    __shared__ __align__(16) short Bs[128 * 32];
    __shared__ __align__(16) short Eh[128 * 136];   // 128 rows x 128 cols, pad +8
    const int tid = threadIdx.x;
    const int w = tid >> 6, lane = tid & 63;
    const int tm = blockIdx.x * 128;
    const int wm = (w & 1) * 64, wn = (w >> 1) * 64;
    const int r = lane & 15, q = lane >> 4, qk = q * 8;

    const int c0 = w * 2, c1 = w * 2 + 1;
    const int srow0 = c0 * 16 + (lane >> 2);
    const int srow1 = c1 * 16 + (lane >> 2);
    const int skk = (lane & 3) * 8;
    const short* gA0 = h + (size_t)(tm + srow0) * 512 + skk;
    const short* gA1 = h + (size_t)(tm + srow1) * 512 + skk;
    short* lA0 = &As[c0 * 512]; short* lA1 = &As[c1 * 512];
    short* lB0 = &Bs[c0 * 512]; short* lB1 = &Bs[c1 * 512];

    f32x4 fused[2][2] = {};
    for (int e = 0; e < 16; ++e) {
        f32x4 acc2[2][2] = {};
        for (int half = 0; half < 2; ++half) {
            const int h0 = half * 128;
            const short* gW0 = We1t + (size_t)(e * 256 + h0 + srow0) * 512 + skk;
            const short* gW1 = We1t + (size_t)(e * 256 + h0 + srow1) * 512 + skk;
            f32x4 acc1[4][4] = {};
            for (int k0 = 0; k0 < 512; k0 += 32) {
                gload16(gA0 + k0, lA0);
                gload16(gA1 + k0, lA1);
                gload16(gW0 + k0, lB0);
                gload16(gW1 + k0, lB1);
                __syncthreads();
                short8 a[4], b[4];
#pragma unroll
                for (int i = 0; i < 4; i++) a[i] = *(const short8*)&As[(wm + i * 16 + r) * 32 + qk];
#pragma unroll
                for (int j = 0; j < 4; j++) b[j] = *(const short8*)&Bs[(wn + j * 16 + r) * 32 + qk];
#pragma unroll
                for (int i = 0; i < 4; i++)
#pragma unroll
                    for (int j = 0; j < 4; j++)
                        acc1[i][j] = __builtin_amdgcn_mfma_f32_16x16x32_bf16(a[i], b[j], acc1[i][j], 0, 0, 0);
                __syncthreads();
            }
            // write eh half (relu + bias) into padded LDS
#pragma unroll
            for (int j = 0; j < 4; j++) {
                int col = wn + j * 16 + r;                 // 0..127 within half
                float bj = be1[e * 256 + h0 + col];
#pragma unroll
                for (int i = 0; i < 4; i++)
#pragma unroll
                    for (int rr = 0; rr < 4; rr++) {
                        int row = wm + i * 16 + q * 4 + rr;
                        Eh[row * 136 + col] = f2b(fmaxf(acc1[i][j][rr] + bj, 0.f));
                    }
            }
            __syncthreads();
            // GEMM2 partial: actions += eh_half @ We2[h0:h0+128, :]
#pragma unroll
            for (int ks = 0; ks < 4; ++ks) {
                short8 a2[2], b2[2];
#pragma unroll
                for (int i2 = 0; i2 < 2; i2++)
                    a2[i2] = *(const short8*)&Eh[(w * 32 + i2 * 16 + r) * 136 + ks * 32 + qk];
#pragma unroll
                for (int j2 = 0; j2 < 2; j2++)
                    b2[j2] = *(const short8*)(We2t + (size_t)(e * 32 + j2 * 16 + r) * 256 + h0 + ks * 32 + qk);
#pragma unroll
                for (int i2 = 0; i2 < 2; i2++)
#pragma unroll
                    for (int j2 = 0; j2 < 2; j2++)
                        acc2[i2][j2] = __builtin_amdgcn_mfma_f32_16x16x32_bf16(a2[i2], b2[j2], acc2[i2][j2], 0, 0, 0);
            }
            __syncthreads();
        }
        // fused += wsel[:,e] * (actions + be2[e])
#pragma unroll
        for (int i2 = 0; i2 < 2; i2++)
#pragma unroll
            for (int rr = 0; rr < 4; rr++) {
                int row = tm + w * 32 + i2 * 16 + q * 4 + rr;
                float wsv = wsel[(size_t)row * 16 + e];
#pragma unroll
                for (int j2 = 0; j2 < 2; j2++) {
                    int col = j2 * 16 + r;
                    fused[i2][j2][rr] += wsv * (acc2[i2][j2][rr] + be2[e * 32 + col]);
                }
            }
    }
#pragma unroll
    for (int i2 = 0; i2 < 2; i2++)
#pragma unroll
        for (int rr = 0; rr < 4; rr++) {
            int row = tm + w * 32 + i2 * 16 + q * 4 + rr;
#pragma unroll
            for (int j2 = 0; j2 < 2; j2++)
                out[(size_t)row * 32 + j2 * 16 + r] = fused[i2][j2][rr];
        }
}

extern "C" void kernel_launch(void* const* d_in, const int* in_sizes, int n_in,
                              void* d_out, int out_size, void* d_ws, size_t ws_size,
                              hipStream_t stream) {
    const float* obs = (const float*)d_in[0];
    const float* Wb0 = (const float*)d_in[1]; const float* bb0 = (const float*)d_in[2];
    const float* Wb1 = (const float*)d_in[3]; const float* bb1 = (const float*)d_in[4];
    const float* Wb2 = (const float*)d_in[5]; const float* bb2 = (const float*)d_in[6];
    const float* We1 = (const float*)d_in[7]; const float* be1 = (const float*)d_in[8];
    const float* We2 = (const float*)d_in[9]; const float* be2 = (const float*)d_in[10];
    const float* Ws0 = (const float*)d_in[11]; const float* bs0 = (const float*)d_in[12];
    const float* Ws1 = (const float*)d_in[13]; const float* bs1 = (const float*)d_in[14];
    const float* Ws2 = (const float*)d_in[15]; const float* bs2 = (const float*)d_in[16];

    const int B = 65536;
    char* ws = (char*)d_ws;
    size_t off = 0;
    auto alloc = [&](size_t bytes) { void* p = ws + off; off += (bytes + 255) & ~(size_t)255; return p; };
    short* obs_bf = (short*)alloc((size_t)B * 512 * 2);
    short* h1     = (short*)alloc((size_t)B * 1024 * 2);
    short* h2     = (short*)alloc((size_t)B * 1024 * 2);
    short* hbuf   = (short*)alloc((size_t)B * 512 * 2);
    short* s0     = (short*)alloc((size_t)B * 256 * 2);
    short* s1     = (short*)alloc((size_t)B * 128 * 2);
    float* wsel   = (float*)alloc((size_t)B * 16 * 4);
    short* Wb0t   = (short*)alloc((size_t)512 * 1024 * 2);
    short* Wb1t   = (short*)alloc((size_t)1024 * 1024 * 2);
    short* Wb2t   = (short*)alloc((size_t)1024 * 512 * 2);
    short* We1t   = (short*)alloc((size_t)16 * 512 * 256 * 2);
    short* We2t   = (short*)alloc((size_t)16 * 256 * 32 * 2);
    short* Ws0t   = (short*)alloc((size_t)512 * 256 * 2);
    short* Ws1t   = (short*)alloc((size_t)256 * 128 * 2);
    short* Ws2t   = (short*)alloc((size_t)128 * 16 * 2);

    // --- preprocessing: casts / transposes ---
    cast_bf16_kernel<<<(B * 512 / 8 + 255) / 256, 256, 0, stream>>>(obs, obs_bf, B * 512 / 8);
    transpose_cast_kernel<<<dim3((1024 * 512 / 8 + 255) / 256, 1), 256, 0, stream>>>(Wb0, Wb0t, 512, 1024, 1024 * 512 / 8);
    transpose_cast_kernel<<<dim3((1024 * 1024 / 8 + 255) / 256, 1), 256, 0, stream>>>(Wb1, Wb1t, 1024, 1024, 1024 * 1024 / 8);
    transpose_cast_kernel<<<dim3((512 * 1024 / 8 + 255) / 256, 1), 256, 0, stream>>>(Wb2, Wb2t, 1024, 512, 512 * 1024 / 8);
    transpose_cast_kernel<<<dim3((256 * 512 / 8 + 255) / 256, 16), 256, 0, stream>>>(We1, We1t, 512, 256, 256 * 512 / 8);
    transpose_cast_kernel<<<dim3((32 * 256 / 8 + 255) / 256, 16), 256, 0, stream>>>(We2, We2t, 256, 32, 32 * 256 / 8);
    transpose_cast_kernel<<<dim3((256 * 512 / 8 + 255) / 256, 1), 256, 0, stream>>>(Ws0, Ws0t, 512, 256, 256 * 512 / 8);
    transpose_cast_kernel<<<dim3((128 * 256 / 8 + 255) / 256, 1), 256, 0, stream>>>(Ws1, Ws1t, 256, 128, 128 * 256 / 8);
    transpose_cast_kernel<<<dim3((16 * 128 / 8 + 255) / 256, 1), 256, 0, stream>>>(Ws2, Ws2t, 128, 16, 16 * 128 / 8);

    // --- selector chain ---
    gemm_bt_bias_relu<<<dim3(256 / 128, B / 128), 256, 0, stream>>>(obs_bf, Ws0t, bs0, s0, B, 256, 512);
    gemm_bt_bias_relu<<<dim3(128 / 128, B / 128), 256, 0, stream>>>(s0, Ws1t, bs1, s1, B, 128, 256);
    selector_softmax<<<B / 16, 256, 0, stream>>>(s1, Ws2t, bs2, wsel);

    // --- backbone ---
    gemm_bt_bias_relu<<<dim3(1024 / 128, B / 128), 256, 0, stream>>>(obs_bf, Wb0t, bb0, h1, B, 1024, 512);
    gemm_bt_bias_relu<<<dim3(1024 / 128, B / 128), 256, 0, stream>>>(h1, Wb1t, bb1, h2, B, 1024, 1024);
    gemm_bt_bias_relu<<<dim3(512 / 128, B / 128), 256, 0, stream>>>(h2, Wb2t, bb2, hbuf, B, 512, 1024);

    // --- fused experts + weighted fusion ---
    expert_fused<<<B / 128, 256, 0, stream>>>(hbuf, We1t, We2t, be1, be2, wsel, (float*)d_out);
}